// Round 5
// baseline (2431.072 us; speedup 1.0000x reference)
//
#include <hip/hip_runtime.h>
#include <hip/hip_bf16.h>

// Problem constants (fixed by setup_inputs)
#define H    300
#define KP   320            // K padded to multiple of 32
#define BM   2048           // num molecules
#define SEG  48
#define NTOK (BM*SEG)       // 98304
#define G    900            // 3*H
#define GW   1024           // padded weight rows (gi order): 19ct*48 = 912, pad to 1024
#define XPW  912            // xp row stride (gi cols; 912 = 19*48)
#define MOLW 32             // molecules per recurrent workgroup
#define NPAIR (MOLW*150)    // bf16-pairs of gate state per wg = 4800
#define PIT  10             // pointwise iters: ceil(NPAIR/512)
#define NT   57             // real gi row tiles (912/16)
#define NCH  10             // K-chunks of 32 (KP/32)
#define BKX  64             // xp_gemm K-step

typedef __attribute__((ext_vector_type(8))) short short8;
typedef __attribute__((ext_vector_type(4))) float f32x4;

__device__ __forceinline__ float lo16(unsigned u) { return __uint_as_float(u << 16); }
__device__ __forceinline__ float hi16(unsigned u) { return __uint_as_float(u & 0xffff0000u); }
__device__ __forceinline__ unsigned short bfb(float f) {
    __hip_bfloat16 b = __float2bfloat16(f);
    return *(unsigned short*)&b;
}
__device__ __forceinline__ void gload16(const void* g, void* l) {
    __builtin_amdgcn_global_load_lds((const __attribute__((address_space(1))) unsigned*)g,
                                     (__attribute__((address_space(3))) unsigned*)l, 16, 0, 0);
}
// lgkm-only barrier: makes ds_writes visible WITHOUT draining vmcnt (keeps DMA prefetch alive)
#define LBAR() do { asm volatile("s_waitcnt lgkmcnt(0)" ::: "memory"); __builtin_amdgcn_s_barrier(); } while (0)

// gate-interleaved row map: R = ct*48 + g*16 + i  <->  original gate-row g*300 + ct*16 + i
// ---------------- prep: weights -> gi-ordered padded bf16, biases -> gi-ordered f32 ----------------
__global__ void prep_weights(const float* wih_f, const float* whh_f, const float* bih_f,
                             const float* wih_b, const float* whh_b, const float* bih_b,
                             __hip_bfloat16* wih, __hip_bfloat16* whh, float* bih) {
    int idx = blockIdx.x * 256 + threadIdx.x;
    const int wn = 2 * GW * KP;
    if (idx < wn) {                          // w_ih (gi rows)
        int d = idx / (GW * KP);
        int R = (idx / KP) % GW;
        int k = idx % KP;
        int ct = R / 48, rem = R % 48, g = rem / 16, i = rem % 16;
        int col = ct * 16 + i;
        const float* src = d ? wih_b : wih_f;
        float v = (R < 912 && col < H && k < H) ? src[(g * H + col) * H + k] : 0.f;
        wih[idx] = __float2bfloat16(v);
        return;
    }
    idx -= wn;
    if (idx < wn) {                          // w_hh (gi rows, same geometry)
        int d = idx / (GW * KP);
        int R = (idx / KP) % GW;
        int k = idx % KP;
        int ct = R / 48, rem = R % 48, g = rem / 16, i = rem % 16;
        int col = ct * 16 + i;
        const float* src = d ? whh_b : whh_f;
        float v = (R < 912 && col < H && k < H) ? src[(g * H + col) * H + k] : 0.f;
        whh[idx] = __float2bfloat16(v);
        return;
    }
    idx -= wn;
    if (idx < 2 * GW) {                      // b_ih (gi rows)
        int d = idx / GW;
        int R = idx % GW;
        int ct = R / 48, rem = R % 48, g = rem / 16, i = rem % 16;
        int col = ct * 16 + i;
        const float* src = d ? bih_b : bih_f;
        bih[idx] = (R < 912 && col < H) ? src[g * H + col] : 0.f;
    }
}

// ---------------- prep: message = bf16(relu(x + bias)), K-padded ----------------
__global__ void prep_msg(const float* x, const float* bias, __hip_bfloat16* msg) {
    int idx = blockIdx.x * 256 + threadIdx.x;      // over NTOK*KP
    if (idx >= NTOK * KP) return;
    int i = idx / KP, k = idx % KP;
    float v = 0.f;
    if (k < H) {
        v = x[i * H + k] + bias[k];
        v = v > 0.f ? v : 0.f;
    }
    msg[idx] = __float2bfloat16(v);
}

// ---------------- prep: h0 = segment_max(x) ----------------
__global__ void h0_kernel(const float* x, float* h0) {
    int m = blockIdx.x;
    for (int c = threadIdx.x; c < H; c += blockDim.x) {
        const float* base = x + (long long)m * SEG * H + c;
        float v = -INFINITY;
        for (int t = 0; t < SEG; t++) v = fmaxf(v, base[t * H]);
        h0[m * H + c] = v;
    }
}

// ---------------- xp = msg @ w_ih^T + b_ih  (m97-style; output cols in gi order) ----------------
__global__ __launch_bounds__(256) void xp_gemm(const __hip_bfloat16* msg, const __hip_bfloat16* wih,
                                               const float* bih, __hip_bfloat16* xp) {
    int d = blockIdx.z;
    const __hip_bfloat16* A  = msg;
    const __hip_bfloat16* Bw = wih + d * GW * KP;
    const float* bi = bih + d * GW;
    __hip_bfloat16* out = xp + (long long)d * NTOK * XPW;

    __shared__ __hip_bfloat16 sA[128 * BKX];   // 16 KB
    __shared__ __hip_bfloat16 sB[128 * BKX];   // 16 KB
    const short* sAs = (const short*)sA;
    const short* sBs = (const short*)sB;

    int tid = threadIdx.x;
    int lane = tid & 63, wid = tid >> 6;
    int l15 = lane & 15, quad = lane >> 4;
    int mblk = blockIdx.x * 128, nblk = blockIdx.y * 128;
    int mbase = (wid >> 1) * 64, nbase = (wid & 1) * 64;

    int srow = wid * 32 + (lane >> 3);          // local row at j=0 (rows += 8 per j)
    int scc  = (lane & 7) ^ (srow & 7);         // swizzled source chunk-in-row
    const short* gA0 = (const short*)A  + (long long)(mblk + srow) * KP + scc * 8;
    const short* gB0 = (const short*)Bw + (long long)(nblk + srow) * KP + scc * 8;
    int xsw = (l15 & 7) << 3;                   // read-side XOR (shorts)

    f32x4 acc[4][4] = {};
    for (int kc = 0; kc < KP / BKX; kc++) {
#pragma unroll
        for (int j = 0; j < 4; j++)
            gload16(gA0 + (long long)j * 8 * KP + kc * BKX, (char*)sA + (wid * 4 + j) * 1024);
#pragma unroll
        for (int j = 0; j < 4; j++)
            gload16(gB0 + (long long)j * 8 * KP + kc * BKX, (char*)sB + (wid * 4 + j) * 1024);
        __syncthreads();

        short8 af[4][2], bf[4][2];
#pragma unroll
        for (int i = 0; i < 4; i++)
#pragma unroll
            for (int kh = 0; kh < 2; kh++)
                af[i][kh] = *(const short8*)(sAs + (mbase + i * 16 + l15) * BKX + ((kh * 32 + quad * 8) ^ xsw));
#pragma unroll
        for (int j = 0; j < 4; j++)
#pragma unroll
            for (int kh = 0; kh < 2; kh++)
                bf[j][kh] = *(const short8*)(sBs + (nbase + j * 16 + l15) * BKX + ((kh * 32 + quad * 8) ^ xsw));
#pragma unroll
        for (int i = 0; i < 4; i++)
#pragma unroll
            for (int j = 0; j < 4; j++) {
                acc[i][j] = __builtin_amdgcn_mfma_f32_16x16x32_bf16(af[i][0], bf[j][0], acc[i][j], 0, 0, 0);
                acc[i][j] = __builtin_amdgcn_mfma_f32_16x16x32_bf16(af[i][1], bf[j][1], acc[i][j], 0, 0, 0);
            }
        __syncthreads();
    }

#pragma unroll
    for (int i = 0; i < 4; i++)
#pragma unroll
        for (int j = 0; j < 4; j++) {
            int col = nblk + nbase + j * 16 + l15;
            if (col < XPW) {
                float bv = bi[col];
#pragma unroll
                for (int r = 0; r < 4; r++) {
                    int row = mblk + mbase + i * 16 + quad * 4 + r;
                    out[(long long)row * XPW + col] = __float2bfloat16(acc[i][j][r] + bv);
                }
            }
        }
}

// ---------------- persistent bidirectional GRU, counted-vmcnt DMA-staged weights ----------------
// grid 128 x 512thr (8 waves, 1 WG/CU on 128 CUs). Direction segregated by XCD (blk%8<4 -> dir0)
// so per-XCD L2 weight set is 0.64MB -> L2-resident. w_hh streamed per step as 10 x 64KB K-chunks
// via global_load_lds, double-buffered, ONE-ahead issue with s_waitcnt vmcnt(8) (never 0 in loop).
// hp (bf16) is deposited into the freed chunk-8 buffer; pair-thread pointwise (coalesced xp/out).
__global__ __launch_bounds__(512, 2) void gru_kernel(const __hip_bfloat16* whh_all, const float* bhh_f,
                                                     const float* bhh_b, const __hip_bfloat16* xp,
                                                     const float* h0, float* out) {
    int b = blockIdx.x;                 // 0..127
    int d = (b >> 2) & 1;               // XCD blk%8: 0-3 -> dir0, 4-7 -> dir1
    int grp = (b >> 3) * 4 + (b & 3);   // 0..63
    const char* whhd = (const char*)(whh_all + (long long)d * GW * KP);
    const float* bhh = d ? bhh_b : bhh_f;
    const __hip_bfloat16* xpd = xp + (long long)d * NTOK * XPW;

    int tid = threadIdx.x;
    int lane = tid & 63, wid = tid >> 6;   // wid 0..7
    int l15 = lane & 15, quad = lane >> 4;

    __shared__ __hip_bfloat16 hB[MOLW * 328];   // 20,992 B  h state (A-operand), stride 328
    __shared__ char bufA[65536];                // chunk double buffer
    __shared__ char bufB[65536];

    int mol0 = grp * MOLW;

    // ---- DMA source pointers: granule Gx = tid + j*512; LDS linear dest, XOR-swizzled source ----
    const char* sb[8];
#pragma unroll
    for (int j = 0; j < 8; j++) {
        int Gx = tid + j * 512;
        int R = Gx >> 2;
        int gsw = (Gx & 3) ^ (R & 3) ^ ((R >> 2) & 3);
        sb[j] = whhd + R * (KP * 2) + gsw * 16;
    }
    int swz = (l15 & 3) ^ ((l15 >> 2) & 3);
    int gq = ((quad ^ swz) & 3) << 4;      // swizzled granule byte-offset for b-frag reads

    // ---- per-wave tile biases (tiles nt = wid + 8k, gi cols decomposed to raw bhh) ----
    float bvw[8];
#pragma unroll
    for (int k = 0; k < 8; k++) {
        int nt = wid + 8 * k;
        float v = 0.f;
        if (nt < NT) {
            int gcol = nt * 16 + l15;
            int ct = gcol / 48, rem = gcol % 48;
            int g = rem >> 4, i = rem & 15;
            int col = ct * 16 + i;
            if (col < H) v = bhh[g * H + col];
        }
        bvw[k] = v;
    }

    // ---- zero hB (incl. K-pad cols 300..327) ----
    for (int e = tid; e < MOLW * 328; e += 512) hB[e] = __float2bfloat16(0.f);
    __syncthreads();

    // ---- init h state (pair-thread ownership) + hB bf16 copy ----
    float hv0[PIT], hv1[PIT];
#pragma unroll
    for (int i = 0; i < PIT; i++) {
        int e2 = tid + i * 512;
        if (e2 < NPAIR) {
            int m = e2 / 150, p = e2 % 150;
            int c = (p >> 3) * 16 + (p & 7) * 2;
            float2 hh = *(const float2*)(h0 + (size_t)(mol0 + m) * H + c);
            hv0[i] = hh.x; hv1[i] = hh.y;
            unsigned pack = ((unsigned)bfb(hh.y) << 16) | bfb(hh.x);
            *(unsigned*)(&hB[m * 328 + c]) = pack;
        }
    }
    LBAR();   // h-init visible; vmcnt untouched

    // ---- stage chunk 0 -> bufA ----
#pragma unroll
    for (int j = 0; j < 8; j++)
        gload16(sb[j], bufA + tid * 16 + j * 8192);

    for (int t = 0; t < SEG; t++) {
        int tt = d ? (SEG - 1 - t) : t;
        char* be = (t & 1) ? bufB : bufA;   // even chunks of this step
        char* bo = (t & 1) ? bufA : bufB;   // odd chunks

        f32x4 acc[8][2] = {};
#pragma unroll
        for (int c = 0; c < NCH; c++) {
            char* cur = (c & 1) ? bo : be;
            char* nxt = (c & 1) ? be : bo;
            if (c < NCH - 1) {
#pragma unroll
                for (int j = 0; j < 8; j++)
                    gload16(sb[j] + (c + 1) * 64, nxt + tid * 16 + j * 8192);
                asm volatile("s_waitcnt vmcnt(8)" ::: "memory");   // chunk c landed; c+1 in flight
            } else {
                asm volatile("s_waitcnt vmcnt(0)" ::: "memory");   // last chunk: full drain
            }
            __builtin_amdgcn_s_barrier();
            // A fragments (2 row-blocks of 16 mols) from hB
            short8 aq0 = *(const short8*)((const char*)hB + l15 * 656 + c * 64 + quad * 16);
            short8 aq1 = *(const short8*)((const char*)hB + (16 + l15) * 656 + c * 64 + quad * 16);
#pragma unroll
            for (int k = 0; k < 8; k++) {
                int nt = wid + 8 * k;
                if (nt < NT) {
                    short8 bq = *(const short8*)(cur + (nt * 16 + l15) * 64 + gq);
                    acc[k][0] = __builtin_amdgcn_mfma_f32_16x16x32_bf16(aq0, bq, acc[k][0], 0, 0, 0);
                    acc[k][1] = __builtin_amdgcn_mfma_f32_16x16x32_bf16(aq1, bq, acc[k][1], 0, 0, 0);
                }
            }
            __builtin_amdgcn_s_barrier();   // reads of `cur` done -> next phase may DMA into it
        }

        // ---- hp = acc + bias -> bf16 into `be` (chunk-8 buffer, free since phase-9 pre-barrier) ----
#pragma unroll
        for (int k = 0; k < 8; k++) {
            int nt = wid + 8 * k;
            if (nt < NT) {
                int gcol = nt * 16 + l15;
#pragma unroll
                for (int rb = 0; rb < 2; rb++)
#pragma unroll
                    for (int r = 0; r < 4; r++) {
                        int mol = rb * 16 + quad * 4 + r;
                        *(__hip_bfloat16*)(be + mol * (XPW * 2) + gcol * 2) =
                            __float2bfloat16(acc[k][rb][r] + bvw[k]);
                    }
            }
        }
        LBAR();   // hp visible; chunk-0-next NOT yet issued, vmcnt preserved

        // ---- pointwise GRU gates (pair-thread, gi dword offsets) ----
#pragma unroll
        for (int i = 0; i < PIT; i++) {
            int e2 = tid + i * 512;
            if (e2 < NPAIR) {
                int m = e2 / 150, p = e2 % 150;
                int ct = p >> 3, i2 = (p & 7) * 2;
                int gib = ct * 48 + i2;
                int c = ct * 16 + i2;
                const __hip_bfloat16* hprow = (const __hip_bfloat16*)(be + m * (XPW * 2));
                unsigned hr2 = *(const unsigned*)(hprow + gib);
                unsigned hz2 = *(const unsigned*)(hprow + gib + 16);
                unsigned hn2 = *(const unsigned*)(hprow + gib + 32);
                long long tok = (long long)(mol0 + m) * SEG + tt;
                const __hip_bfloat16* xrow = xpd + tok * XPW;
                unsigned xr2 = *(const unsigned*)(xrow + gib);
                unsigned xz2 = *(const unsigned*)(xrow + gib + 16);
                unsigned xn2 = *(const unsigned*)(xrow + gib + 32);

                float xr0 = lo16(xr2), xr1 = hi16(xr2);
                float xz0 = lo16(xz2), xz1 = hi16(xz2);
                float xn0 = lo16(xn2), xn1 = hi16(xn2);
                float hr0 = lo16(hr2), hr1 = hi16(hr2);
                float hz0 = lo16(hz2), hz1 = hi16(hz2);
                float hn0 = lo16(hn2), hn1 = hi16(hn2);

                float rg0 = 1.f / (1.f + __expf(-(xr0 + hr0)));
                float rg1 = 1.f / (1.f + __expf(-(xr1 + hr1)));
                float zg0 = 1.f / (1.f + __expf(-(xz0 + hz0)));
                float zg1 = 1.f / (1.f + __expf(-(xz1 + hz1)));
                float ni0 = xn0 + rg0 * hn0;
                float ni1 = xn1 + rg1 * hn1;
                float ng0 = 1.f - 2.f / (__expf(2.f * ni0) + 1.f);
                float ng1 = 1.f - 2.f / (__expf(2.f * ni1) + 1.f);
                float h0n = (1.f - zg0) * ng0 + zg0 * hv0[i];
                float h1n = (1.f - zg1) * ng1 + zg1 * hv1[i];
                hv0[i] = h0n; hv1[i] = h1n;

                unsigned pack = ((unsigned)bfb(h1n) << 16) | bfb(h0n);
                *(unsigned*)(&hB[m * 328 + c]) = pack;
                *(float2*)(out + tok * 600 + d * 300 + c) = make_float2(h0n, h1n);
            }
        }
        // ---- issue next step's chunk 0 -> bo (chunk-9 buffer; reads done). After the out-stores
        //      so stores are OLDER in the vmcnt FIFO -> next phase-0 vmcnt(8) stays exact. ----
#pragma unroll
        for (int j = 0; j < 8; j++)
            gload16(sb[j], bo + tid * 16 + j * 8192);
        LBAR();   // hB/hp-read ordering across waves; does NOT drain chunk-0 DMA
    }
}

extern "C" void kernel_launch(void* const* d_in, const int* in_sizes, int n_in,
                              void* d_out, int out_size, void* d_ws, size_t ws_size,
                              hipStream_t stream) {
    const float* x     = (const float*)d_in[0];
    const float* bias  = (const float*)d_in[4];
    const float* wih_f = (const float*)d_in[5];
    const float* whh_f = (const float*)d_in[6];
    const float* bih_f = (const float*)d_in[7];
    const float* bhh_f = (const float*)d_in[8];
    const float* wih_b = (const float*)d_in[9];
    const float* whh_b = (const float*)d_in[10];
    const float* bih_b = (const float*)d_in[11];
    const float* bhh_b = (const float*)d_in[12];
    float* out = (float*)d_out;

    // Workspace layout (total 426,614,784 B ~= 406.9 MiB)
    char* ws = (char*)d_ws;
    __hip_bfloat16* msg = (__hip_bfloat16*)(ws);                    //  62,914,560 B
    __hip_bfloat16* wih = (__hip_bfloat16*)(ws + 62914560LL);       //   1,310,720 B
    __hip_bfloat16* whh = (__hip_bfloat16*)(ws + 64225280LL);       //   1,310,720 B (gi, 1024 rows/dir)
    float*          bih = (float*)         (ws + 65536000LL);       //       8,192 B
    float*          h0  = (float*)         (ws + 65544192LL);       //   2,457,600 B
    __hip_bfloat16* xp  = (__hip_bfloat16*)(ws + 68001792LL);       // 358,612,992 B

    hipLaunchKernelGGL(prep_weights, dim3((2*GW*KP + 2*GW*KP + 2*GW + 255) / 256), dim3(256), 0, stream,
                       wih_f, whh_f, bih_f, wih_b, whh_b, bih_b, wih, whh, bih);
    hipLaunchKernelGGL(prep_msg, dim3((NTOK * KP + 255) / 256), dim3(256), 0, stream, x, bias, msg);
    hipLaunchKernelGGL(h0_kernel, dim3(BM), dim3(256), 0, stream, x, h0);
    hipLaunchKernelGGL(xp_gemm, dim3(NTOK / 128, GW / 128, 2), dim3(256), 0, stream, msg, wih, bih, xp);
    hipLaunchKernelGGL(gru_kernel, dim3(128), dim3(512), 0, stream, whh, bhh_f, bhh_b, xp, h0, out);
}

// Round 8
// 2006.913 us; speedup vs baseline: 1.2113x; 1.2113x over previous
//
#include <hip/hip_runtime.h>
#include <hip/hip_bf16.h>

// Problem constants (fixed by setup_inputs)
#define H    300
#define KP   320            // K padded to multiple of 32
#define BM   2048           // num molecules
#define SEG  48
#define NTOK (BM*SEG)       // 98304
#define G    900            // 3*H
#define GW   1024           // padded weight rows (gi order): 19ct*48 = 912, pad to 1024
#define XPW  912            // xp row stride (gi cols; 912 = 19*48)
#define MOLW 32             // molecules per recurrent workgroup
#define WGT  1024           // gru threads: 16 waves -> 4 waves/SIMD on active CUs
#define NPAIR (MOLW*150)    // bf16-pairs of gate state per wg = 4800
#define PIT  5              // pointwise iters: ceil(NPAIR/WGT)
#define NT   57             // real gi row tiles (912/16)
#define NCH  10             // K-chunks of 32 (KP/32)
#define BKX  64             // xp_gemm K-step

typedef __attribute__((ext_vector_type(8))) short short8;
typedef __attribute__((ext_vector_type(4))) float f32x4;
typedef __attribute__((ext_vector_type(2))) float f32x2;

__device__ __forceinline__ float lo16(unsigned u) { return __uint_as_float(u << 16); }
__device__ __forceinline__ float hi16(unsigned u) { return __uint_as_float(u & 0xffff0000u); }
__device__ __forceinline__ unsigned short bfb(float f) {
    __hip_bfloat16 b = __float2bfloat16(f);
    return *(unsigned short*)&b;
}
__device__ __forceinline__ void gload16(const void* g, void* l) {
    __builtin_amdgcn_global_load_lds((const __attribute__((address_space(1))) unsigned*)g,
                                     (__attribute__((address_space(3))) unsigned*)l, 16, 0, 0);
}
// lgkm-only barrier: makes ds_writes visible WITHOUT draining vmcnt (keeps DMA prefetch alive)
#define LBAR() do { asm volatile("s_waitcnt lgkmcnt(0)" ::: "memory"); __builtin_amdgcn_s_barrier(); } while (0)

// gate-interleaved row map: R = ct*48 + g*16 + i  <->  original gate-row g*300 + ct*16 + i
// ---------------- prep: weights -> gi-ordered padded bf16, biases -> gi-ordered f32 ----------------
__global__ void prep_weights(const float* wih_f, const float* whh_f, const float* bih_f,
                             const float* wih_b, const float* whh_b, const float* bih_b,
                             __hip_bfloat16* wih, __hip_bfloat16* whh, float* bih) {
    int idx = blockIdx.x * 256 + threadIdx.x;
    const int wn = 2 * GW * KP;
    if (idx < wn) {                          // w_ih (gi rows)
        int d = idx / (GW * KP);
        int R = (idx / KP) % GW;
        int k = idx % KP;
        int ct = R / 48, rem = R % 48, g = rem / 16, i = rem % 16;
        int col = ct * 16 + i;
        const float* src = d ? wih_b : wih_f;
        float v = (R < 912 && col < H && k < H) ? src[(g * H + col) * H + k] : 0.f;
        wih[idx] = __float2bfloat16(v);
        return;
    }
    idx -= wn;
    if (idx < wn) {                          // w_hh (gi rows, same geometry)
        int d = idx / (GW * KP);
        int R = (idx / KP) % GW;
        int k = idx % KP;
        int ct = R / 48, rem = R % 48, g = rem / 16, i = rem % 16;
        int col = ct * 16 + i;
        const float* src = d ? whh_b : whh_f;
        float v = (R < 912 && col < H && k < H) ? src[(g * H + col) * H + k] : 0.f;
        whh[idx] = __float2bfloat16(v);
        return;
    }
    idx -= wn;
    if (idx < 2 * GW) {                      // b_ih (gi rows)
        int d = idx / GW;
        int R = idx % GW;
        int ct = R / 48, rem = R % 48, g = rem / 16, i = rem % 16;
        int col = ct * 16 + i;
        const float* src = d ? bih_b : bih_f;
        bih[idx] = (R < 912 && col < H) ? src[g * H + col] : 0.f;
    }
}

// ---------------- prep: message = bf16(relu(x + bias)), K-padded ----------------
__global__ void prep_msg(const float* x, const float* bias, __hip_bfloat16* msg) {
    int idx = blockIdx.x * 256 + threadIdx.x;      // over NTOK*KP
    if (idx >= NTOK * KP) return;
    int i = idx / KP, k = idx % KP;
    float v = 0.f;
    if (k < H) {
        v = x[i * H + k] + bias[k];
        v = v > 0.f ? v : 0.f;
    }
    msg[idx] = __float2bfloat16(v);
}

// ---------------- prep: h0 = segment_max(x) ----------------
__global__ void h0_kernel(const float* x, float* h0) {
    int m = blockIdx.x;
    for (int c = threadIdx.x; c < H; c += blockDim.x) {
        const float* base = x + (long long)m * SEG * H + c;
        float v = -INFINITY;
        for (int t = 0; t < SEG; t++) v = fmaxf(v, base[t * H]);
        h0[m * H + c] = v;
    }
}

// ---------------- xp = msg @ w_ih^T + b_ih  (m97-style; output cols in gi order) ----------------
__global__ __launch_bounds__(256) void xp_gemm(const __hip_bfloat16* msg, const __hip_bfloat16* wih,
                                               const float* bih, __hip_bfloat16* xp) {
    int d = blockIdx.z;
    const __hip_bfloat16* A  = msg;
    const __hip_bfloat16* Bw = wih + d * GW * KP;
    const float* bi = bih + d * GW;
    __hip_bfloat16* out = xp + (long long)d * NTOK * XPW;

    __shared__ __hip_bfloat16 sA[128 * BKX];   // 16 KB
    __shared__ __hip_bfloat16 sB[128 * BKX];   // 16 KB
    const short* sAs = (const short*)sA;
    const short* sBs = (const short*)sB;

    int tid = threadIdx.x;
    int lane = tid & 63, wid = tid >> 6;
    int l15 = lane & 15, quad = lane >> 4;
    int mblk = blockIdx.x * 128, nblk = blockIdx.y * 128;
    int mbase = (wid >> 1) * 64, nbase = (wid & 1) * 64;

    int srow = wid * 32 + (lane >> 3);          // local row at j=0 (rows += 8 per j)
    int scc  = (lane & 7) ^ (srow & 7);         // swizzled source chunk-in-row
    const short* gA0 = (const short*)A  + (long long)(mblk + srow) * KP + scc * 8;
    const short* gB0 = (const short*)Bw + (long long)(nblk + srow) * KP + scc * 8;
    int xsw = (l15 & 7) << 3;                   // read-side XOR (shorts)

    f32x4 acc[4][4] = {};
    for (int kc = 0; kc < KP / BKX; kc++) {
#pragma unroll
        for (int j = 0; j < 4; j++)
            gload16(gA0 + (long long)j * 8 * KP + kc * BKX, (char*)sA + (wid * 4 + j) * 1024);
#pragma unroll
        for (int j = 0; j < 4; j++)
            gload16(gB0 + (long long)j * 8 * KP + kc * BKX, (char*)sB + (wid * 4 + j) * 1024);
        __syncthreads();

        short8 af[4][2], bf[4][2];
#pragma unroll
        for (int i = 0; i < 4; i++)
#pragma unroll
            for (int kh = 0; kh < 2; kh++)
                af[i][kh] = *(const short8*)(sAs + (mbase + i * 16 + l15) * BKX + ((kh * 32 + quad * 8) ^ xsw));
#pragma unroll
        for (int j = 0; j < 4; j++)
#pragma unroll
            for (int kh = 0; kh < 2; kh++)
                bf[j][kh] = *(const short8*)(sBs + (nbase + j * 16 + l15) * BKX + ((kh * 32 + quad * 8) ^ xsw));
#pragma unroll
        for (int i = 0; i < 4; i++)
#pragma unroll
            for (int j = 0; j < 4; j++) {
                acc[i][j] = __builtin_amdgcn_mfma_f32_16x16x32_bf16(af[i][0], bf[j][0], acc[i][j], 0, 0, 0);
                acc[i][j] = __builtin_amdgcn_mfma_f32_16x16x32_bf16(af[i][1], bf[j][1], acc[i][j], 0, 0, 0);
            }
        __syncthreads();
    }

#pragma unroll
    for (int i = 0; i < 4; i++)
#pragma unroll
        for (int j = 0; j < 4; j++) {
            int col = nblk + nbase + j * 16 + l15;
            if (col < XPW) {
                float bv = bi[col];
#pragma unroll
                for (int r = 0; r < 4; r++) {
                    int row = mblk + mbase + i * 16 + quad * 4 + r;
                    out[(long long)row * XPW + col] = __float2bfloat16(acc[i][j][r] + bv);
                }
            }
        }
}

// ---------------- persistent bidirectional GRU, counted-vmcnt DMA-staged weights ----------------
// grid 128 x 1024thr (16 waves, 4 waves/SIMD, 1 WG/CU via 152KB LDS). Direction segregated by
// XCD (blk%8<4 -> dir0) so per-XCD L2 weight set is 0.64MB. w_hh streamed per step as 10 x 64KB
// K-chunks via global_load_lds, double-buffered, one-ahead with s_waitcnt vmcnt(4) (never 0 in
// the chunk loop). xp reads / out writes use NON-TEMPORAL hints so the streaming traffic doesn't
// evict the L2-resident weights (R5's FETCH excess = ~790MB of weight re-fetch from HBM).
// NOTE: 128 WGs (not 256) is deliberate — per-WG weight stream is MOLW-independent, so 256 WGs
// would double L2 demand (~32 TB/s, near the 34.5 ceiling) without cutting step time.
__global__ __launch_bounds__(WGT) void gru_kernel(const __hip_bfloat16* whh_all, const float* bhh_f,
                                                  const float* bhh_b, const __hip_bfloat16* xp,
                                                  const float* h0, float* out) {
    int b = blockIdx.x;                 // 0..127
    int d = (b >> 2) & 1;               // XCD blk%8: 0-3 -> dir0, 4-7 -> dir1
    int grp = (b >> 3) * 4 + (b & 3);   // 0..63
    const char* whhd = (const char*)(whh_all + (long long)d * GW * KP);
    const float* bhh = d ? bhh_b : bhh_f;
    const __hip_bfloat16* xpd = xp + (long long)d * NTOK * XPW;

    int tid = threadIdx.x;
    int lane = tid & 63, wid = tid >> 6;   // wid 0..15
    int l15 = lane & 15, quad = lane >> 4;

    __shared__ __hip_bfloat16 hB[MOLW * 328];   // 20,992 B  h state (A-operand), stride 328
    __shared__ char bufA[65536];                // chunk double buffer
    __shared__ char bufB[65536];

    int mol0 = grp * MOLW;

    // ---- DMA source pointers: granule Gx = tid + j*1024; LDS linear dest, XOR-swizzled source ----
    const char* sb[4];
#pragma unroll
    for (int j = 0; j < 4; j++) {
        int Gx = tid + j * WGT;
        int R = Gx >> 2;
        int gsw = (Gx & 3) ^ (R & 3) ^ ((R >> 2) & 3);
        sb[j] = whhd + R * (KP * 2) + gsw * 16;
    }
    int swz = (l15 & 3) ^ ((l15 >> 2) & 3);
    int gq = ((quad ^ swz) & 3) << 4;      // swizzled granule byte-offset for b-frag reads

    // ---- per-wave tile biases (tiles nt = wid + 16k, gi cols decomposed to raw bhh) ----
    float bvw[4];
#pragma unroll
    for (int k = 0; k < 4; k++) {
        int nt = wid + 16 * k;
        float v = 0.f;
        if (nt < NT) {
            int gcol = nt * 16 + l15;
            int ct = gcol / 48, rem = gcol % 48;
            int g = rem >> 4, i = rem & 15;
            int col = ct * 16 + i;
            if (col < H) v = bhh[g * H + col];
        }
        bvw[k] = v;
    }

    // ---- zero hB (incl. K-pad cols 300..327) ----
    for (int e = tid; e < MOLW * 328; e += WGT) hB[e] = __float2bfloat16(0.f);
    __syncthreads();

    // ---- init h state (pair-thread ownership) + hB bf16 copy ----
    float hv0[PIT], hv1[PIT];
#pragma unroll
    for (int i = 0; i < PIT; i++) {
        int e2 = tid + i * WGT;
        if (e2 < NPAIR) {
            int m = e2 / 150, p = e2 % 150;
            int c = (p >> 3) * 16 + (p & 7) * 2;
            float2 hh = *(const float2*)(h0 + (size_t)(mol0 + m) * H + c);
            hv0[i] = hh.x; hv1[i] = hh.y;
            unsigned pack = ((unsigned)bfb(hh.y) << 16) | bfb(hh.x);
            *(unsigned*)(&hB[m * 328 + c]) = pack;
        }
    }
    LBAR();   // h-init visible; vmcnt untouched

    // ---- stage chunk 0 -> bufA ----
#pragma unroll
    for (int j = 0; j < 4; j++)
        gload16(sb[j], bufA + tid * 16 + j * 16384);

    for (int t = 0; t < SEG; t++) {
        int tt = d ? (SEG - 1 - t) : t;
        char* be = (t & 1) ? bufB : bufA;   // even chunks of this step
        char* bo = (t & 1) ? bufA : bufB;   // odd chunks

        f32x4 acc[4][2] = {};
#pragma unroll
        for (int c = 0; c < NCH; c++) {
            char* cur = (c & 1) ? bo : be;
            char* nxt = (c & 1) ? be : bo;
            if (c < NCH - 1) {
#pragma unroll
                for (int j = 0; j < 4; j++)
                    gload16(sb[j] + (c + 1) * 64, nxt + tid * 16 + j * 16384);
                asm volatile("s_waitcnt vmcnt(4)" ::: "memory");   // chunk c landed; c+1 in flight
            } else {
                asm volatile("s_waitcnt vmcnt(0)" ::: "memory");   // last chunk: full drain
            }
            __builtin_amdgcn_s_barrier();
            // A fragments (2 row-blocks of 16 mols) from hB
            short8 aq0 = *(const short8*)((const char*)hB + l15 * 656 + c * 64 + quad * 16);
            short8 aq1 = *(const short8*)((const char*)hB + (16 + l15) * 656 + c * 64 + quad * 16);
#pragma unroll
            for (int k = 0; k < 4; k++) {
                int nt = wid + 16 * k;
                if (nt < NT) {
                    short8 bq = *(const short8*)(cur + (nt * 16 + l15) * 64 + gq);
                    acc[k][0] = __builtin_amdgcn_mfma_f32_16x16x32_bf16(aq0, bq, acc[k][0], 0, 0, 0);
                    acc[k][1] = __builtin_amdgcn_mfma_f32_16x16x32_bf16(aq1, bq, acc[k][1], 0, 0, 0);
                }
            }
            __builtin_amdgcn_s_barrier();   // reads of `cur` done -> next phase may DMA into it
        }

        // ---- hp = acc + bias -> bf16 into `be` (chunk-8 buffer, free after phase-9 entry) ----
#pragma unroll
        for (int k = 0; k < 4; k++) {
            int nt = wid + 16 * k;
            if (nt < NT) {
                int gcol = nt * 16 + l15;
#pragma unroll
                for (int rb = 0; rb < 2; rb++)
#pragma unroll
                    for (int r = 0; r < 4; r++) {
                        int mol = rb * 16 + quad * 4 + r;
                        *(__hip_bfloat16*)(be + mol * (XPW * 2) + gcol * 2) =
                            __float2bfloat16(acc[k][rb][r] + bvw[k]);
                    }
            }
        }
        LBAR();   // hp visible; chunk-0-next NOT yet issued, vmcnt preserved

        // ---- pointwise GRU gates (pair-thread; NT loads/stores on streaming data) ----
#pragma unroll
        for (int i = 0; i < PIT; i++) {
            int e2 = tid + i * WGT;
            if (e2 < NPAIR) {
                int m = e2 / 150, p = e2 % 150;
                int ct = p >> 3, i2 = (p & 7) * 2;
                int gib = ct * 48 + i2;
                int c = ct * 16 + i2;
                const __hip_bfloat16* hprow = (const __hip_bfloat16*)(be + m * (XPW * 2));
                unsigned hr2 = *(const unsigned*)(hprow + gib);
                unsigned hz2 = *(const unsigned*)(hprow + gib + 16);
                unsigned hn2 = *(const unsigned*)(hprow + gib + 32);
                long long tok = (long long)(mol0 + m) * SEG + tt;
                const __hip_bfloat16* xrow = xpd + tok * XPW;
                unsigned xr2 = __builtin_nontemporal_load((const unsigned*)(xrow + gib));
                unsigned xz2 = __builtin_nontemporal_load((const unsigned*)(xrow + gib + 16));
                unsigned xn2 = __builtin_nontemporal_load((const unsigned*)(xrow + gib + 32));

                float xr0 = lo16(xr2), xr1 = hi16(xr2);
                float xz0 = lo16(xz2), xz1 = hi16(xz2);
                float xn0 = lo16(xn2), xn1 = hi16(xn2);
                float hr0 = lo16(hr2), hr1 = hi16(hr2);
                float hz0 = lo16(hz2), hz1 = hi16(hz2);
                float hn0 = lo16(hn2), hn1 = hi16(hn2);

                float rg0 = 1.f / (1.f + __expf(-(xr0 + hr0)));
                float rg1 = 1.f / (1.f + __expf(-(xr1 + hr1)));
                float zg0 = 1.f / (1.f + __expf(-(xz0 + hz0)));
                float zg1 = 1.f / (1.f + __expf(-(xz1 + hz1)));
                float ni0 = xn0 + rg0 * hn0;
                float ni1 = xn1 + rg1 * hn1;
                float ng0 = 1.f - 2.f / (__expf(2.f * ni0) + 1.f);
                float ng1 = 1.f - 2.f / (__expf(2.f * ni1) + 1.f);
                float h0n = (1.f - zg0) * ng0 + zg0 * hv0[i];
                float h1n = (1.f - zg1) * ng1 + zg1 * hv1[i];
                hv0[i] = h0n; hv1[i] = h1n;

                unsigned pack = ((unsigned)bfb(h1n) << 16) | bfb(h0n);
                *(unsigned*)(&hB[m * 328 + c]) = pack;
                f32x2 ov; ov.x = h0n; ov.y = h1n;
                __builtin_nontemporal_store(ov, (f32x2*)(out + tok * 600 + d * 300 + c));
            }
        }
        // ---- issue next step's chunk 0 -> bo (chunk-9 buffer; reads done). After the out-stores
        //      so stores are OLDER in the vmcnt FIFO -> next phase-0 vmcnt(4) stays exact. ----
#pragma unroll
        for (int j = 0; j < 4; j++)
            gload16(sb[j], bo + tid * 16 + j * 16384);
        LBAR();   // hB updates visible across waves; does NOT drain chunk-0 DMA
    }
}

extern "C" void kernel_launch(void* const* d_in, const int* in_sizes, int n_in,
                              void* d_out, int out_size, void* d_ws, size_t ws_size,
                              hipStream_t stream) {
    const float* x     = (const float*)d_in[0];
    const float* bias  = (const float*)d_in[4];
    const float* wih_f = (const float*)d_in[5];
    const float* whh_f = (const float*)d_in[6];
    const float* bih_f = (const float*)d_in[7];
    const float* bhh_f = (const float*)d_in[8];
    const float* wih_b = (const float*)d_in[9];
    const float* whh_b = (const float*)d_in[10];
    const float* bih_b = (const float*)d_in[11];
    const float* bhh_b = (const float*)d_in[12];
    float* out = (float*)d_out;

    // Workspace layout (total 426,614,784 B ~= 406.9 MiB)
    char* ws = (char*)d_ws;
    __hip_bfloat16* msg = (__hip_bfloat16*)(ws);                    //  62,914,560 B
    __hip_bfloat16* wih = (__hip_bfloat16*)(ws + 62914560LL);       //   1,310,720 B
    __hip_bfloat16* whh = (__hip_bfloat16*)(ws + 64225280LL);       //   1,310,720 B (gi, 1024 rows/dir)
    float*          bih = (float*)         (ws + 65536000LL);       //       8,192 B
    float*          h0  = (float*)         (ws + 65544192LL);       //   2,457,600 B
    __hip_bfloat16* xp  = (__hip_bfloat16*)(ws + 68001792LL);       // 358,612,992 B

    hipLaunchKernelGGL(prep_weights, dim3((2*GW*KP + 2*GW*KP + 2*GW + 255) / 256), dim3(256), 0, stream,
                       wih_f, whh_f, bih_f, wih_b, whh_b, bih_b, wih, whh, bih);
    hipLaunchKernelGGL(prep_msg, dim3((NTOK * KP + 255) / 256), dim3(256), 0, stream, x, bias, msg);
    hipLaunchKernelGGL(h0_kernel, dim3(BM), dim3(256), 0, stream, x, h0);
    hipLaunchKernelGGL(xp_gemm, dim3(NTOK / 128, GW / 128, 2), dim3(256), 0, stream, msg, wih, bih, xp);
    hipLaunchKernelGGL(gru_kernel, dim3(128), dim3(WGT), 0, stream, whh, bhh_f, bhh_b, xp, h0, out);
}

// Round 10
// 1506.899 us; speedup vs baseline: 1.6133x; 1.3318x over previous
//
#include <hip/hip_runtime.h>
#include <hip/hip_bf16.h>

// Problem constants (fixed by setup_inputs)
#define H    300
#define KP   320            // K padded to multiple of 32
#define BM   2048           // num molecules
#define SEG  48
#define NTOK (BM*SEG)       // 98304
#define G    900            // 3*H
#define GP   912            // hp width: 57*16
#define NT   57             // GP/16
#define GW   1024           // wih row-pad: 8*128 (B-operand tiles)
#define XPW  912            // xp row stride (cols >= 900 never read; 912 keeps 4B align)
#define MOLW 16             // molecules per recurrent workgroup
#define WGT  1024           // gru workgroup threads (16 waves -> 4 waves/SIMD, 1 WG/CU)
#define NPAIR (MOLW*150)    // bf16-pairs of gate state per wg = 2400
#define PIT  3              // pointwise iters: ceil(NPAIR/WGT)
#define BKX  64             // xp_gemm K-step

typedef __attribute__((ext_vector_type(8))) short short8;
typedef __attribute__((ext_vector_type(4))) float f32x4;

__device__ __forceinline__ float lo16(unsigned u) { return __uint_as_float(u << 16); }
__device__ __forceinline__ float hi16(unsigned u) { return __uint_as_float(u & 0xffff0000u); }
__device__ __forceinline__ unsigned short bfb(float f) {
    __hip_bfloat16 b = __float2bfloat16(f);
    return *(unsigned short*)&b;
}
__device__ __forceinline__ void gload16(const void* g, void* l) {
    __builtin_amdgcn_global_load_lds((const __attribute__((address_space(1))) unsigned*)g,
                                     (__attribute__((address_space(3))) unsigned*)l, 16, 0, 0);
}

// ---------------- prep: weights -> padded bf16, biases -> padded f32 ----------------
__global__ void prep_weights(const float* wih_f, const float* whh_f, const float* bih_f,
                             const float* wih_b, const float* whh_b, const float* bih_b,
                             __hip_bfloat16* wih, __hip_bfloat16* whh, float* bih) {
    int idx = blockIdx.x * 256 + threadIdx.x;
    const int wih_n = 2 * GW * KP;
    const int whh_n = 2 * GP * KP;
    if (idx < wih_n) {
        int d = idx / (GW * KP);
        int r = (idx / KP) % GW;
        int k = idx % KP;
        const float* src = d ? wih_b : wih_f;
        float v = (r < G && k < H) ? src[r * H + k] : 0.f;
        wih[idx] = __float2bfloat16(v);
        return;
    }
    idx -= wih_n;
    if (idx < whh_n) {
        int d = idx / (GP * KP);
        int r = (idx / KP) % GP;
        int k = idx % KP;
        const float* src = d ? whh_b : whh_f;
        float v = (r < G && k < H) ? src[r * H + k] : 0.f;
        whh[idx] = __float2bfloat16(v);
        return;
    }
    idx -= whh_n;
    if (idx < 2 * GW) {
        int d = idx / GW;
        int r = idx % GW;
        const float* src = d ? bih_b : bih_f;
        bih[idx] = (r < G) ? src[r] : 0.f;
    }
}

// ---------------- prep: message = bf16(relu(x + bias)), K-padded ----------------
__global__ void prep_msg(const float* x, const float* bias, __hip_bfloat16* msg) {
    int idx = blockIdx.x * 256 + threadIdx.x;      // over NTOK*KP
    if (idx >= NTOK * KP) return;
    int i = idx / KP, k = idx % KP;
    float v = 0.f;
    if (k < H) {
        v = x[i * H + k] + bias[k];
        v = v > 0.f ? v : 0.f;
    }
    msg[idx] = __float2bfloat16(v);
}

// ---------------- prep: h0 = segment_max(x) ----------------
__global__ void h0_kernel(const float* x, float* h0) {
    int m = blockIdx.x;
    for (int c = threadIdx.x; c < H; c += blockDim.x) {
        const float* base = x + (long long)m * SEG * H + c;
        float v = -INFINITY;
        for (int t = 0; t < SEG; t++) v = fmaxf(v, base[t * H]);
        h0[m * H + c] = v;
    }
}

// ---------------- xp = msg @ w_ih^T + b_ih  (m97-style: global_load_lds staging, 128x128 tile) ----------------
// Measured in R3/R4: non-gru total 546 us with this version (vs 785 us with the m33-style direct one).
__global__ __launch_bounds__(256) void xp_gemm(const __hip_bfloat16* msg, const __hip_bfloat16* wih,
                                               const float* bih, __hip_bfloat16* xp) {
    int d = blockIdx.z;
    const __hip_bfloat16* A  = msg;
    const __hip_bfloat16* Bw = wih + d * GW * KP;
    const float* bi = bih + d * GW;
    __hip_bfloat16* out = xp + (long long)d * NTOK * XPW;

    __shared__ __hip_bfloat16 sA[128 * BKX];   // 16 KB
    __shared__ __hip_bfloat16 sB[128 * BKX];   // 16 KB
    const short* sAs = (const short*)sA;
    const short* sBs = (const short*)sB;

    int tid = threadIdx.x;
    int lane = tid & 63, wid = tid >> 6;
    int l15 = lane & 15, quad = lane >> 4;
    int mblk = blockIdx.x * 128, nblk = blockIdx.y * 128;
    int mbase = (wid >> 1) * 64, nbase = (wid & 1) * 64;

    int srow = wid * 32 + (lane >> 3);          // local row at j=0 (rows += 8 per j)
    int scc  = (lane & 7) ^ (srow & 7);         // swizzled source chunk-in-row
    const short* gA0 = (const short*)A  + (long long)(mblk + srow) * KP + scc * 8;
    const short* gB0 = (const short*)Bw + (long long)(nblk + srow) * KP + scc * 8;
    int xsw = (l15 & 7) << 3;                   // read-side XOR (shorts)

    f32x4 acc[4][4] = {};
    for (int kc = 0; kc < KP / BKX; kc++) {
#pragma unroll
        for (int j = 0; j < 4; j++)
            gload16(gA0 + (long long)j * 8 * KP + kc * BKX, (char*)sA + (wid * 4 + j) * 1024);
#pragma unroll
        for (int j = 0; j < 4; j++)
            gload16(gB0 + (long long)j * 8 * KP + kc * BKX, (char*)sB + (wid * 4 + j) * 1024);
        __syncthreads();   // compiler drains vmcnt before s_barrier -> LDS tiles ready

        short8 af[4][2], bf[4][2];
#pragma unroll
        for (int i = 0; i < 4; i++)
#pragma unroll
            for (int kh = 0; kh < 2; kh++)
                af[i][kh] = *(const short8*)(sAs + (mbase + i * 16 + l15) * BKX + ((kh * 32 + quad * 8) ^ xsw));
#pragma unroll
        for (int j = 0; j < 4; j++)
#pragma unroll
            for (int kh = 0; kh < 2; kh++)
                bf[j][kh] = *(const short8*)(sBs + (nbase + j * 16 + l15) * BKX + ((kh * 32 + quad * 8) ^ xsw));
#pragma unroll
        for (int i = 0; i < 4; i++)
#pragma unroll
            for (int j = 0; j < 4; j++) {
                acc[i][j] = __builtin_amdgcn_mfma_f32_16x16x32_bf16(af[i][0], bf[j][0], acc[i][j], 0, 0, 0);
                acc[i][j] = __builtin_amdgcn_mfma_f32_16x16x32_bf16(af[i][1], bf[j][1], acc[i][j], 0, 0, 0);
            }
        __syncthreads();   // before next kc overwrites LDS
    }

#pragma unroll
    for (int i = 0; i < 4; i++)
#pragma unroll
        for (int j = 0; j < 4; j++) {
            int col = nblk + nbase + j * 16 + l15;
            if (col < XPW) {
                float bv = bi[col];
#pragma unroll
                for (int r = 0; r < 4; r++) {
                    int row = mblk + mbase + i * 16 + quad * 4 + r;
                    out[(long long)row * XPW + col] = __float2bfloat16(acc[i][j][r] + bv);
                }
            }
        }
}

// ---------------- persistent bidirectional GRU over 48 steps ----------------
// MEASURED-BEST gru structure (R2: 948 us, FETCH 0.18 GB, Occ 48%): grid (128, 2) = 256 WGs,
// 1024 thr = 16 waves -> 1 WG/CU on all 256 CUs, register B-loads (L2-behaved, unlike
// global_load_lds which re-fetched weights at 1.2-2 GB/dispatch in R4/R5/R8).
__global__ __launch_bounds__(WGT, 4) void gru_kernel(const __hip_bfloat16* whh_all, const float* bhh_f,
                                                     const float* bhh_b, const __hip_bfloat16* xp,
                                                     const float* h0, float* out) {
    int grp = blockIdx.x;      // molecule group, 0..127
    int d   = blockIdx.y;      // direction
    const short* Ws = (const short*)(whh_all + d * GP * KP);
    const float* bhh = d ? bhh_b : bhh_f;
    const __hip_bfloat16* xpd = xp + (long long)d * NTOK * XPW;

    int tid = threadIdx.x;
    int lane = tid & 63, wid = tid >> 6;           // wid 0..15
    int l15 = lane & 15, quad = lane >> 4;

    __shared__ __hip_bfloat16 hB[MOLW * 328];      // 10,496 B  bf16 h (A-operand), stride 328
    __shared__ __hip_bfloat16 hp[MOLW * GP];       // 29,184 B  recurrent projections (+b_hh)
    const short* hBs = (const short*)hB;

    int mol0 = grp * MOLW;

    // ---- zero hB (incl. K-pad cols 300..327) ----
    for (int e = tid; e < MOLW * 328; e += WGT) hB[e] = __float2bfloat16(0.f);

    // ---- hoist bhh per-wave tile biases (nt = wid + 16k, k<4) ----
    float bvw[4];
#pragma unroll
    for (int k = 0; k < 4; k++) {
        int nt = wid + 16 * k;
        int gc = nt * 16 + l15;
        bvw[k] = (nt < NT && gc < G) ? bhh[gc] : 0.f;
    }
    __syncthreads();   // hB zeros visible before pair-writes below

    // ---- init h state: registers (gate-thread ownership) + hB bf16 copy ----
    float hv0[PIT], hv1[PIT];
#pragma unroll
    for (int i = 0; i < PIT; i++) {
        int e2 = tid + i * WGT;
        if (e2 < NPAIR) {
            int m = e2 / 150, c = 2 * (e2 % 150);
            float2 hh = *(const float2*)(h0 + (size_t)(mol0 + m) * H + c);
            hv0[i] = hh.x; hv1[i] = hh.y;
            unsigned pack = ((unsigned)bfb(hh.y) << 16) | bfb(hh.x);
            *(unsigned*)(&hB[m * 328 + c]) = pack;
        }
    }
    __syncthreads();

    for (int t = 0; t < SEG; t++) {
        int tt = d ? (SEG - 1 - t) : t;

        // ---- issue xp prefetch for this step (global, overlaps GEMM) ----
        unsigned pr[PIT], pz[PIT], pn[PIT];
#pragma unroll
        for (int i = 0; i < PIT; i++) {
            int e2 = tid + i * WGT;
            if (e2 < NPAIR) {
                int m = e2 / 150, c = 2 * (e2 % 150);
                const __hip_bfloat16* xrow = xpd + ((long long)(mol0 + m) * SEG + tt) * XPW;
                pr[i] = *(const unsigned*)(xrow + c);
                pz[i] = *(const unsigned*)(xrow + c + 300);
                pn[i] = *(const unsigned*)(xrow + c + 600);
            }
        }

        // ---- load nt-invariant A-fragments (single 16-row block) ----
        short8 afA[10];
#pragma unroll
        for (int kk = 0; kk < 10; kk++) {
            int koff = kk * 32 + quad * 8;
            afA[kk] = *(const short8*)(hBs + l15 * 328 + koff);
        }

        // ---- GEMM: hp = h @ w_hh^T + b_hh ----
        int k8 = 0;
        for (int nt = wid; nt < NT; nt += 16, k8++) {
            int gcol = nt * 16 + l15;
            const short* bp = Ws + gcol * KP;
            f32x4 acc0 = {0.f, 0.f, 0.f, 0.f};
#pragma unroll
            for (int kk = 0; kk < 10; kk++) {
                short8 b = *(const short8*)(bp + kk * 32 + quad * 8);
                acc0 = __builtin_amdgcn_mfma_f32_16x16x32_bf16(afA[kk], b, acc0, 0, 0, 0);
            }
            float bv = bvw[k8];
#pragma unroll
            for (int r = 0; r < 4; r++)
                hp[(quad * 4 + r) * GP + gcol] = __float2bfloat16(acc0[r] + bv);
        }
        __syncthreads();

        // ---- pointwise GRU gates (fp32, 2 elems/thread/iter) ----
#pragma unroll
        for (int i = 0; i < PIT; i++) {
            int e2 = tid + i * WGT;
            if (e2 < NPAIR) {
                int m = e2 / 150, c = 2 * (e2 % 150);
                unsigned hr2 = *(const unsigned*)(&hp[m * GP + c]);
                unsigned hz2 = *(const unsigned*)(&hp[m * GP + c + 300]);
                unsigned hn2 = *(const unsigned*)(&hp[m * GP + c + 600]);

                float xr0 = lo16(pr[i]), xr1 = hi16(pr[i]);
                float xz0 = lo16(pz[i]), xz1 = hi16(pz[i]);
                float xn0 = lo16(pn[i]), xn1 = hi16(pn[i]);
                float hr0 = lo16(hr2),  hr1 = hi16(hr2);
                float hz0 = lo16(hz2),  hz1 = hi16(hz2);
                float hn0 = lo16(hn2),  hn1 = hi16(hn2);

                float rg0 = 1.f / (1.f + __expf(-(xr0 + hr0)));
                float rg1 = 1.f / (1.f + __expf(-(xr1 + hr1)));
                float zg0 = 1.f / (1.f + __expf(-(xz0 + hz0)));
                float zg1 = 1.f / (1.f + __expf(-(xz1 + hz1)));
                float ni0 = xn0 + rg0 * hn0;
                float ni1 = xn1 + rg1 * hn1;
                float ng0 = 1.f - 2.f / (__expf(2.f * ni0) + 1.f);
                float ng1 = 1.f - 2.f / (__expf(2.f * ni1) + 1.f);
                float h0n = (1.f - zg0) * ng0 + zg0 * hv0[i];
                float h1n = (1.f - zg1) * ng1 + zg1 * hv1[i];
                hv0[i] = h0n; hv1[i] = h1n;

                unsigned pack = ((unsigned)bfb(h1n) << 16) | bfb(h0n);
                *(unsigned*)(&hB[m * 328 + c]) = pack;

                long long tok = (long long)(mol0 + m) * SEG + tt;
                *(float2*)(out + tok * 600 + d * 300 + c) = make_float2(h0n, h1n);
            }
        }
        __syncthreads();
    }
}

extern "C" void kernel_launch(void* const* d_in, const int* in_sizes, int n_in,
                              void* d_out, int out_size, void* d_ws, size_t ws_size,
                              hipStream_t stream) {
    const float* x     = (const float*)d_in[0];
    const float* bias  = (const float*)d_in[4];
    const float* wih_f = (const float*)d_in[5];
    const float* whh_f = (const float*)d_in[6];
    const float* bih_f = (const float*)d_in[7];
    const float* bhh_f = (const float*)d_in[8];
    const float* wih_b = (const float*)d_in[9];
    const float* whh_b = (const float*)d_in[10];
    const float* bih_b = (const float*)d_in[11];
    const float* bhh_b = (const float*)d_in[12];
    float* out = (float*)d_out;

    // Workspace layout (total 426,471,424 B ~= 406.7 MiB)
    char* ws = (char*)d_ws;
    __hip_bfloat16* msg = (__hip_bfloat16*)(ws);                    //  62,914,560 B
    __hip_bfloat16* wih = (__hip_bfloat16*)(ws + 62914560LL);       //   1,310,720 B
    __hip_bfloat16* whh = (__hip_bfloat16*)(ws + 64225280LL);       //   1,167,360 B
    float*          bih = (float*)         (ws + 65392640LL);       //       8,192 B
    float*          h0  = (float*)         (ws + 65400832LL);       //   2,457,600 B
    __hip_bfloat16* xp  = (__hip_bfloat16*)(ws + 67858432LL);       // 358,612,992 B

    hipLaunchKernelGGL(prep_weights, dim3((2*GW*KP + 2*GP*KP + 2*GW + 255) / 256), dim3(256), 0, stream,
                       wih_f, whh_f, bih_f, wih_b, whh_b, bih_b, wih, whh, bih);
    hipLaunchKernelGGL(prep_msg, dim3((NTOK * KP + 255) / 256), dim3(256), 0, stream, x, bias, msg);
    hipLaunchKernelGGL(h0_kernel, dim3(BM), dim3(256), 0, stream, x, h0);
    hipLaunchKernelGGL(xp_gemm, dim3(NTOK / 128, GW / 128, 2), dim3(256), 0, stream, msg, wih, bih, xp);
    hipLaunchKernelGGL(gru_kernel, dim3(BM / MOLW, 2), dim3(WGT), 0, stream, whh, bhh_f, bhh_b, xp, h0, out);
}